// Round 10
// baseline (12214.630 us; speedup 1.0000x reference)
//
#include <hip/hip_runtime.h>
#include <math.h>

#define Bb 128
#define Tt 1024
#define Ff 128
#define Hh 256
#define Oo 128

#define NW 192u  // resident weight u32s per thread

// d_ws layout (u32 words)
#define P_PACK 0u
#define PACK_SZ  (2u * NW * 512u)          // 196608
#define P_FLAG (P_PACK + PACK_SZ)          // 256 flags: [rowset2][128]
#define P_HX   (P_FLAG + 256u)             // [buf2][rowset2][128 blk][64]
#define HXS    64u
#define P_PART (P_HX + 2u * 2u * 128u * HXS)

typedef _Float16 half2_t __attribute__((ext_vector_type(2)));
union U32H2 { unsigned u; half2_t h; };

__device__ __forceinline__ float dot2f(unsigned wu, unsigned hu, float acc) {
    U32H2 a, b; a.u = wu; b.u = hu;
#if __has_builtin(__builtin_amdgcn_fdot2)
    return __builtin_amdgcn_fdot2(a.h, b.h, acc, false);
#else
    return acc + (float)a.h.x * (float)b.h.x + (float)a.h.y * (float)b.h.y;
#endif
}

// R4/R9-validated pack: dst[(role*NW + j)*512 + tid]
__global__ void pack_kernel(const float* __restrict__ wih, const float* __restrict__ whh,
                            const float* __restrict__ wsel, const float* __restrict__ wout,
                            unsigned* __restrict__ dst) {
    unsigned pid = blockIdx.x * 256 + threadIdx.x;
    if (pid >= 2u * NW * 512u) return;
    int tid = pid & 511;
    int j = (pid >> 9) % NW;
    int role = pid / (NW * 512u);
    int d = tid & 127, q = tid >> 7;
    int orow = tid & 63, oct = tid >> 6;
    const float* src; int idx0;
    if (j < 96) {
        int g = j >> 5, p = j & 31;
        int R = g * 256 + role * 128 + d;
        src = whh; idx0 = R * 256 + 2 * (32 * q + p);
    } else if (j < 144) {
        int jj = j - 96, g = jj >> 4, p = jj & 15;
        int R = g * 256 + role * 128 + d;
        src = wih; idx0 = R * 128 + 2 * (16 * q + p);
    } else if (j < 160) {
        int jj = j - 144;
        src = wsel; idx0 = d * 256 + 2 * (role * 64 + q * 16 + jj);
    } else if (j < 176) {
        int jj = j - 160;
        src = wsel; idx0 = d * 256 + 2 * ((1 - role) * 64 + q * 16 + jj);
    } else {
        int jj = j - 176;
        int R = role * 64 + orow;
        src = wout; idx0 = R * 256 + 2 * (oct * 16 + jj);
    }
    U32H2 v; v.h = (half2_t){ (_Float16)src[idx0], (_Float16)src[idx0 + 1] };
    dst[pid] = v.u;
}

__global__ void zero_flags(unsigned* __restrict__ flags) { flags[threadIdx.x] = 0u; }

__global__ __launch_bounds__(512)
void gru_kernel(const float* __restrict__ x, const float* __restrict__ noise,
                const float* __restrict__ bih, const float* __restrict__ bhh,
                const float* __restrict__ bout, const float* __restrict__ bsel,
                unsigned* __restrict__ wsu,
                float* __restrict__ outputs, float* __restrict__ selw,
                float* __restrict__ partials) {
    const int bid = blockIdx.x;           // 0..127
    const int p   = bid & 63;
    const int role = bid >> 6;            // partner = bid^64 (same XCD mod 8; perf only)
    const int rA = p, rB = 64 + p;        // two rows per pair, ping-pong
    const int tid = threadIdx.x;
    const int d = tid & 127, q = tid >> 7;
    const int orow = tid & 63, oct = tid >> 6;

    __shared__ unsigned h2uA[128], h2uB[128];   // full h as fp16 pairs
    __shared__ unsigned wxuA[64],  wxuB[64];    // gated inputs
    __shared__ float redA[512 * 5], redB[512 * 5];

    // ---- resident weights (R9 layout; lives in unified VGPR+AGPR file) ----
    unsigned whh2[96], wih2[48], wselo[16], wselp[16], wout2[16];
    const unsigned base = (unsigned)(role * NW) * 512u + (unsigned)tid;
    const unsigned* __restrict__ pk = wsu + P_PACK;
    #pragma unroll
    for (int j = 0; j < 96; j++) whh2[j] = pk[base + j * 512];
    #pragma unroll
    for (int j = 0; j < 48; j++) wih2[j] = pk[base + (96 + j) * 512];
    #pragma unroll
    for (int j = 0; j < 16; j++) wselo[j] = pk[base + (144 + j) * 512];
    #pragma unroll
    for (int j = 0; j < 16; j++) wselp[j] = pk[base + (160 + j) * 512];
    #pragma unroll
    for (int j = 0; j < 16; j++) wout2[j] = pk[base + (176 + j) * 512];
    #pragma unroll
    for (int j = 0; j < 96; j++) asm volatile("" : "+v"(whh2[j]));
    #pragma unroll
    for (int j = 0; j < 48; j++) asm volatile("" : "+v"(wih2[j]));
    #pragma unroll
    for (int j = 0; j < 16; j++) asm volatile("" : "+v"(wselo[j]));
    #pragma unroll
    for (int j = 0; j < 16; j++) asm volatile("" : "+v"(wselp[j]));
    #pragma unroll
    for (int j = 0; j < 16; j++) asm volatile("" : "+v"(wout2[j]));

    // ---- biases ----
    float bias_r = 0.f, bias_z = 0.f, bias_in = 0.f, bias_hn = 0.f, bsel_d = 0.f, bout_o = 0.f;
    if (tid < 128) {
        int gr = role * 128 + d;
        bias_r  = bih[gr]       + bhh[gr];
        bias_z  = bih[256 + gr] + bhh[256 + gr];
        bias_in = bih[512 + gr];
        bias_hn = bhh[512 + gr];
        bsel_d  = bsel[d];
    }
    if (tid < 64) bout_o = bout[role * 64 + tid];

    // ---- init both rows ----
    if (tid < 128) {
        h2uA[tid] = 0u; h2uB[tid] = 0u;
        float xa = x[(size_t)rA * Tt * Ff + tid];
        float xap = __shfl_xor(xa, 1, 64);
        float xb = x[(size_t)rB * Tt * Ff + tid];
        float xbp = __shfl_xor(xb, 1, 64);
        if (!(tid & 1)) {
            U32H2 v; v.h = (half2_t){ (_Float16)xa, (_Float16)xap }; wxuA[tid >> 1] = v.u;
            U32H2 w; w.h = (half2_t){ (_Float16)xb, (_Float16)xbp }; wxuB[tid >> 1] = w.u;
        }
        if (role == 0) {
            selw[(size_t)rA * Ff + tid] = 1.0f;
            selw[(size_t)rB * Ff + tid] = 1.0f;
        }
    }
    __syncthreads();

    unsigned* flags = wsu + P_FLAG;
    unsigned* hx    = wsu + P_HX;
    const unsigned myIdx = (unsigned)(p * 2 + role);
    const unsigned pIdx  = (unsigned)(p * 2 + (role ^ 1));

    float h_oldA = 0.f, h_oldB = 0.f, ssumA = 0.f, ssumB = 0.f;
    size_t xbaseA  = ((size_t)rA * Tt + 1) * Ff + d;
    size_t xbaseB  = ((size_t)rB * Tt + 1) * Ff + d;
    size_t nzbaseA = (size_t)rA * Ff + d;
    size_t nzbaseB = (size_t)rB * Ff + d;
    size_t swbaseA = ((size_t)Bb + rA) * Ff + d;
    size_t swbaseB = ((size_t)Bb + rB) * Ff + d;
    size_t obaseA  = (size_t)rA * Oo + role * 64 + orow;
    size_t obaseB  = (size_t)rB * Oo + role * 64 + orow;

    const uint4* h4A = (const uint4*)h2uA;
    const uint4* h4B = (const uint4*)h2uB;
    const uint4* w4A = (const uint4*)wxuA;
    const uint4* w4B = (const uint4*)wxuB;

    #define GATES(h4_, w4_, red_)                                                   \
    {                                                                               \
        float a_r = 0.f, a_z = 0.f, a_in = 0.f, a_hn = 0.f;                         \
        _Pragma("unroll")                                                           \
        for (int pp = 0; pp < 8; ++pp) {                                            \
            uint4 hv = h4_[8 * q + pp];                                             \
            unsigned hh[4] = { hv.x, hv.y, hv.z, hv.w };                            \
            _Pragma("unroll")                                                       \
            for (int i = 0; i < 4; i++) {                                           \
                a_r  = dot2f(whh2[pp * 4 + i],      hh[i], a_r);                    \
                a_z  = dot2f(whh2[32 + pp * 4 + i], hh[i], a_z);                    \
                a_hn = dot2f(whh2[64 + pp * 4 + i], hh[i], a_hn);                   \
            }                                                                       \
        }                                                                           \
        _Pragma("unroll")                                                           \
        for (int pp = 0; pp < 4; ++pp) {                                            \
            uint4 wv = w4_[4 * q + pp];                                             \
            unsigned ww[4] = { wv.x, wv.y, wv.z, wv.w };                            \
            _Pragma("unroll")                                                       \
            for (int i = 0; i < 4; i++) {                                           \
                a_r  = dot2f(wih2[pp * 4 + i],      ww[i], a_r);                    \
                a_z  = dot2f(wih2[16 + pp * 4 + i], ww[i], a_z);                    \
                a_in = dot2f(wih2[32 + pp * 4 + i], ww[i], a_in);                   \
            }                                                                       \
        }                                                                           \
        red_[tid * 5 + 0] = a_r; red_[tid * 5 + 1] = a_z;                           \
        red_[tid * 5 + 2] = a_in; red_[tid * 5 + 3] = a_hn;                         \
    }

    #define HFIN(red_, h2u_, h_old_)                                                \
    if (tid < 128) {                                                                \
        float rr = bias_r, zz = bias_z, ii = bias_in, hh = bias_hn;                 \
        _Pragma("unroll")                                                           \
        for (int qq = 0; qq < 4; qq++) {                                            \
            int b0 = (qq * 128 + d) * 5;                                            \
            rr += red_[b0]; zz += red_[b0 + 1]; ii += red_[b0 + 2]; hh += red_[b0 + 3]; \
        }                                                                           \
        float r_ = 1.f / (1.f + expf(-rr));                                         \
        float z_ = 1.f / (1.f + expf(-zz));                                         \
        float n_ = tanhf(ii + r_ * hh);                                             \
        float hn2 = (1.f - z_) * n_ + z_ * h_old_;                                  \
        h_old_ = hn2;                                                               \
        float hp = __shfl_xor(hn2, 1, 64);                                          \
        if (!(d & 1)) {                                                             \
            U32H2 v; v.h = (half2_t){ (_Float16)hn2, (_Float16)hp };                \
            h2u_[role * 64 + (d >> 1)] = v.u;                                       \
        }                                                                           \
    }

    for (int t = 0; t < Tt; ++t) {
        // prefetch inputs for both rows (consumed in EA/EB)
        float xvA = 0.f, nzvA = 0.f, xvB = 0.f, nzvB = 0.f;
        if (tid < 128 && t < Tt - 1) {
            xvA = x[xbaseA]; nzvA = noise[nzbaseA];
            xvB = x[xbaseB]; nzvB = noise[nzbaseB];
        }

        const unsigned mbMyA = (((unsigned)(t & 1) * 2u + 0u) * 128u + myIdx) * HXS;
        const unsigned mbPA  = (((unsigned)(t & 1) * 2u + 0u) * 128u + pIdx)  * HXS;
        const unsigned mbMyB = (((unsigned)(t & 1) * 2u + 1u) * 128u + myIdx) * HXS;
        const unsigned mbPB  = (((unsigned)(t & 1) * 2u + 1u) * 128u + pIdx)  * HXS;

        // P1: gates A
        GATES(h4A, w4A, redA)
        __syncthreads();                              // B1
        // P2: finalize hA -> LDS own half
        HFIN(redA, h2uA, h_oldA)
        __syncthreads();                              // B2
        // P3: wave0 publishes hA + flagA (drains own stores only); all: gates B
        if (tid < 64)
            __hip_atomic_store(&hx[mbMyA + tid], h2uA[role * 64 + tid],
                               __ATOMIC_RELAXED, __HIP_MEMORY_SCOPE_AGENT);
        if (tid == 0) {
            asm volatile("s_waitcnt vmcnt(0)" ::: "memory");
            __hip_atomic_store(&flags[0 * 128 + myIdx], (unsigned)(t + 1),
                               __ATOMIC_RELAXED, __HIP_MEMORY_SCOPE_AGENT);
        }
        GATES(h4B, w4B, redB)
        __syncthreads();                              // B3
        // P4: finalize hB -> LDS own half
        HFIN(redB, h2uB, h_oldB)
        __syncthreads();                              // B4

        // P5: wave0 publishes hB + flagB; all: own-half projections A and B;
        //     wave0 then spins for partner hA (message had P3..P5 to fly)
        if (tid < 64)
            __hip_atomic_store(&hx[mbMyB + tid], h2uB[role * 64 + tid],
                               __ATOMIC_RELAXED, __HIP_MEMORY_SCOPE_AGENT);
        if (tid == 0) {
            asm volatile("s_waitcnt vmcnt(0)" ::: "memory");
            __hip_atomic_store(&flags[1 * 128 + myIdx], (unsigned)(t + 1),
                               __ATOMIC_RELAXED, __HIP_MEMORY_SCOPE_AGENT);
        }
        float pselA = 0.f, poutA = 0.f, pselB = 0.f, poutB = 0.f;
        #pragma unroll
        for (int mm = 0; mm < 4; ++mm) {
            uint4 ha = h4A[role * 16 + q * 4 + mm];
            unsigned a_[4] = { ha.x, ha.y, ha.z, ha.w };
            uint4 hb = h4B[role * 16 + q * 4 + mm];
            unsigned b_[4] = { hb.x, hb.y, hb.z, hb.w };
            #pragma unroll
            for (int i = 0; i < 4; i++) {
                pselA = dot2f(wselo[mm * 4 + i], a_[i], pselA);
                pselB = dot2f(wselo[mm * 4 + i], b_[i], pselB);
            }
        }
        if ((oct >> 2) == role) {
            #pragma unroll
            for (int mm = 0; mm < 4; ++mm) {
                uint4 ha = h4A[oct * 4 + mm];
                unsigned a_[4] = { ha.x, ha.y, ha.z, ha.w };
                uint4 hb = h4B[oct * 4 + mm];
                unsigned b_[4] = { hb.x, hb.y, hb.z, hb.w };
                #pragma unroll
                for (int i = 0; i < 4; i++) {
                    poutA = dot2f(wout2[mm * 4 + i], a_[i], poutA);
                    poutB = dot2f(wout2[mm * 4 + i], b_[i], poutB);
                }
            }
        }
        if (tid < 64) {
            while (__hip_atomic_load(&flags[0 * 128 + pIdx], __ATOMIC_RELAXED,
                                     __HIP_MEMORY_SCOPE_AGENT) < (unsigned)(t + 1))
                __builtin_amdgcn_s_sleep(1);
            asm volatile("" ::: "memory");    // forbid hoisting the data load above the spin
            unsigned pv = __hip_atomic_load(&hx[mbPA + tid], __ATOMIC_RELAXED,
                                            __HIP_MEMORY_SCOPE_AGENT);
            h2uA[(role ^ 1) * 64 + tid] = pv;
        }
        __syncthreads();                              // B5

        // P6: partner-half projections A; stash to redA
        #pragma unroll
        for (int mm = 0; mm < 4; ++mm) {
            uint4 ha = h4A[(role ^ 1) * 16 + q * 4 + mm];
            unsigned a_[4] = { ha.x, ha.y, ha.z, ha.w };
            #pragma unroll
            for (int i = 0; i < 4; i++) pselA = dot2f(wselp[mm * 4 + i], a_[i], pselA);
        }
        if ((oct >> 2) != role) {
            #pragma unroll
            for (int mm = 0; mm < 4; ++mm) {
                uint4 ha = h4A[oct * 4 + mm];
                unsigned a_[4] = { ha.x, ha.y, ha.z, ha.w };
                #pragma unroll
                for (int i = 0; i < 4; i++) poutA = dot2f(wout2[mm * 4 + i], a_[i], poutA);
            }
        }
        redA[tid * 5 + 0] = pselA; redA[tid * 5 + 1] = poutA;
        __syncthreads();                              // B6

        // P7: finalize row A (outputs, w, wx); wave0 spins for partner hB
        if (tid < 64) {
            float acc = bout_o;
            #pragma unroll
            for (int j = 0; j < 8; j++) acc += redA[(j * 64 + tid) * 5 + 1];
            outputs[obaseA] = acc;
            while (__hip_atomic_load(&flags[1 * 128 + pIdx], __ATOMIC_RELAXED,
                                     __HIP_MEMORY_SCOPE_AGENT) < (unsigned)(t + 1))
                __builtin_amdgcn_s_sleep(1);
            asm volatile("" ::: "memory");
            unsigned pv = __hip_atomic_load(&hx[mbPB + tid], __ATOMIC_RELAXED,
                                            __HIP_MEMORY_SCOPE_AGENT);
            h2uB[(role ^ 1) * 64 + tid] = pv;
        }
        if (tid < 128 && t < Tt - 1) {
            float lg = bsel_d;
            #pragma unroll
            for (int qq = 0; qq < 4; qq++) lg += redA[(qq * 128 + d) * 5 + 0];
            float arg = (lg + logf(nzvA + 1e-20f) - logf(1.f - nzvA + 1e-20f)) * 20.0f;
            float w = 1.f / (1.f + expf(-arg));
            if (role == 0) { selw[swbaseA] = w; ssumA += w; }
            float wxv = w * xvA;
            float wp = __shfl_xor(wxv, 1, 64);
            if (!(d & 1)) {
                U32H2 v; v.h = (half2_t){ (_Float16)wxv, (_Float16)wp };
                wxuA[d >> 1] = v.u;
            }
        }
        __syncthreads();                              // B7

        // P8: partner-half projections B; stash to redB
        #pragma unroll
        for (int mm = 0; mm < 4; ++mm) {
            uint4 hb = h4B[(role ^ 1) * 16 + q * 4 + mm];
            unsigned b_[4] = { hb.x, hb.y, hb.z, hb.w };
            #pragma unroll
            for (int i = 0; i < 4; i++) pselB = dot2f(wselp[mm * 4 + i], b_[i], pselB);
        }
        if ((oct >> 2) != role) {
            #pragma unroll
            for (int mm = 0; mm < 4; ++mm) {
                uint4 hb = h4B[oct * 4 + mm];
                unsigned b_[4] = { hb.x, hb.y, hb.z, hb.w };
                #pragma unroll
                for (int i = 0; i < 4; i++) poutB = dot2f(wout2[mm * 4 + i], b_[i], poutB);
            }
        }
        redB[tid * 5 + 0] = pselB; redB[tid * 5 + 1] = poutB;
        __syncthreads();                              // B8

        // P9: finalize row B
        if (tid < 64) {
            float acc = bout_o;
            #pragma unroll
            for (int j = 0; j < 8; j++) acc += redB[(j * 64 + tid) * 5 + 1];
            outputs[obaseB] = acc;
        }
        if (tid < 128 && t < Tt - 1) {
            float lg = bsel_d;
            #pragma unroll
            for (int qq = 0; qq < 4; qq++) lg += redB[(qq * 128 + d) * 5 + 0];
            float arg = (lg + logf(nzvB + 1e-20f) - logf(1.f - nzvB + 1e-20f)) * 20.0f;
            float w = 1.f / (1.f + expf(-arg));
            if (role == 0) { selw[swbaseB] = w; ssumB += w; }
            float wxv = w * xvB;
            float wp = __shfl_xor(wxv, 1, 64);
            if (!(d & 1)) {
                U32H2 v; v.h = (half2_t){ (_Float16)wxv, (_Float16)wp };
                wxuB[d >> 1] = v.u;
            }
        }
        __syncthreads();                              // B9

        obaseA += (size_t)Bb * Oo;  obaseB += (size_t)Bb * Oo;
        nzbaseA += (size_t)Bb * Ff; nzbaseB += (size_t)Bb * Ff;
        swbaseA += (size_t)Bb * Ff; swbaseB += (size_t)Bb * Ff;
        xbaseA += Ff;               xbaseB += Ff;
    }

    // ---- per-row selection-sum partials (role-0 blocks) ----
    if (role == 0) {
        redA[tid] = (tid < 128) ? ssumA : 0.f;
        redB[tid] = (tid < 128) ? ssumB : 0.f;
        __syncthreads();
        for (int s = 256; s > 0; s >>= 1) {
            if (tid < s) { redA[tid] += redA[tid + s]; redB[tid] += redB[tid + s]; }
            __syncthreads();
        }
        if (tid == 0) { partials[rA] = redA[0]; partials[rB] = redB[0]; }
    }
}

__global__ void finalize_kernel(const float* __restrict__ partials, float* __restrict__ out_scalar) {
    __shared__ float red[128];
    int t = threadIdx.x;
    red[t] = partials[t];
    __syncthreads();
    for (int s = 64; s > 0; s >>= 1) {
        if (t < s) red[t] += red[t + s];
        __syncthreads();
    }
    if (t == 0) out_scalar[0] = red[0];
}

extern "C" void kernel_launch(void* const* d_in, const int* in_sizes, int n_in,
                              void* d_out, int out_size, void* d_ws, size_t ws_size,
                              hipStream_t stream) {
    const float* x     = (const float*)d_in[0];
    const float* noise = (const float*)d_in[1];
    const float* w_ih  = (const float*)d_in[2];
    const float* w_hh  = (const float*)d_in[3];
    const float* b_ih  = (const float*)d_in[4];
    const float* b_hh  = (const float*)d_in[5];
    const float* W_out = (const float*)d_in[6];
    const float* b_out = (const float*)d_in[7];
    const float* W_sel = (const float*)d_in[8];
    const float* b_sel = (const float*)d_in[9];

    unsigned* wsu = (unsigned*)d_ws;
    float* out = (float*)d_out;
    float* outputs = out;                               // [T,B,O]
    float* nsel    = out + (size_t)Tt * Bb * Oo;        // scalar
    float* selw    = nsel + 1;                          // [T,B,F]
    float* partials = (float*)(wsu + P_PART);

    pack_kernel<<<(2 * NW * 512 + 255) / 256, 256, 0, stream>>>(w_ih, w_hh, W_sel, W_out, wsu);
    zero_flags<<<1, 256, 0, stream>>>(wsu + P_FLAG);
    gru_kernel<<<128, 512, 0, stream>>>(x, noise, b_ih, b_hh, b_out, b_sel,
                                        wsu, outputs, selw, partials);
    finalize_kernel<<<1, 128, 0, stream>>>(partials, nsel);
}

// Round 11
// 4621.192 us; speedup vs baseline: 2.6432x; 2.6432x over previous
//
#include <hip/hip_runtime.h>
#include <math.h>

#define Bb 128
#define Tt 1024
#define Ff 128
#define Hh 256
#define Oo 128

#define NW 192u  // resident weight u32s per thread

// d_ws layout (u32 words)
#define P_PACK 0u
#define PACK_SZ  (2u * NW * 512u)          // 196608
#define P_FLAG (P_PACK + PACK_SZ)          // 256 flags
#define P_HX   (P_FLAG + 256u)             // 2 bufs * 256 * 64 u32
#define HXS    64u
#define P_PART (P_HX + 2u * 256u * HXS)

typedef _Float16 half2_t __attribute__((ext_vector_type(2)));
union U32H2 { unsigned u; half2_t h; };

__device__ __forceinline__ float dot2f(unsigned wu, unsigned hu, float acc) {
    U32H2 a, b; a.u = wu; b.u = hu;
#if __has_builtin(__builtin_amdgcn_fdot2)
    return __builtin_amdgcn_fdot2(a.h, b.h, acc, false);
#else
    return acc + (float)a.h.x * (float)b.h.x + (float)a.h.y * (float)b.h.y;
#endif
}

// Raw barrier: drain LDS only (lgkm), leave global store acks in flight.
// Compiler fences on both sides pin LDS op ordering around the barrier.
#define BAR_LGKM() do {                                              \
    asm volatile("s_waitcnt lgkmcnt(0)" ::: "memory");               \
    __builtin_amdgcn_s_barrier();                                    \
    asm volatile("" ::: "memory");                                   \
} while (0)

// R4/R9-validated pack: dst[(role*NW + j)*512 + tid]
__global__ void pack_kernel(const float* __restrict__ wih, const float* __restrict__ whh,
                            const float* __restrict__ wsel, const float* __restrict__ wout,
                            unsigned* __restrict__ dst) {
    unsigned pid = blockIdx.x * 256 + threadIdx.x;
    if (pid >= 2u * NW * 512u) return;
    int tid = pid & 511;
    int j = (pid >> 9) % NW;
    int role = pid / (NW * 512u);
    int d = tid & 127, q = tid >> 7;
    int orow = tid & 63, oct = tid >> 6;
    const float* src; int idx0;
    if (j < 96) {
        int g = j >> 5, p = j & 31;
        int R = g * 256 + role * 128 + d;
        src = whh; idx0 = R * 256 + 2 * (32 * q + p);
    } else if (j < 144) {
        int jj = j - 96, g = jj >> 4, p = jj & 15;
        int R = g * 256 + role * 128 + d;
        src = wih; idx0 = R * 128 + 2 * (16 * q + p);
    } else if (j < 160) {
        int jj = j - 144;
        src = wsel; idx0 = d * 256 + 2 * (role * 64 + q * 16 + jj);
    } else if (j < 176) {
        int jj = j - 160;
        src = wsel; idx0 = d * 256 + 2 * ((1 - role) * 64 + q * 16 + jj);
    } else {
        int jj = j - 176;
        int R = role * 64 + orow;
        src = wout; idx0 = R * 256 + 2 * (oct * 16 + jj);
    }
    U32H2 v; v.h = (half2_t){ (_Float16)src[idx0], (_Float16)src[idx0 + 1] };
    dst[pid] = v.u;
}

__global__ void zero_flags(unsigned* __restrict__ flags) { flags[threadIdx.x] = 0u; }

__global__ __launch_bounds__(512)
void gru_kernel(const float* __restrict__ x, const float* __restrict__ noise,
                const float* __restrict__ bih, const float* __restrict__ bhh,
                const float* __restrict__ bout, const float* __restrict__ bsel,
                unsigned* __restrict__ wsu,
                float* __restrict__ outputs, float* __restrict__ selw,
                float* __restrict__ partials) {
    const int bid = blockIdx.x;
    const int row = bid & 127;
    const int role = bid >> 7;            // pair (row, row+128): same XCD mod-8 (perf only)
    const int tid = threadIdx.x;
    const int d = tid & 127, q = tid >> 7;
    const int orow = tid & 63, oct = tid >> 6;

    __shared__ unsigned h2u[128];         // full h as fp16 pairs
    __shared__ unsigned wxu[64];          // gated input as fp16 pairs
    __shared__ float red[512 * 5];        // stride-5 padded partials

    // ---- resident weights (R9 layout; VGPR+AGPR unified file) ----
    unsigned whh2[96], wih2[48], wselo[16], wselp[16], wout2[16];
    const unsigned base = (unsigned)(role * NW) * 512u + (unsigned)tid;
    const unsigned* __restrict__ pk = wsu + P_PACK;
    #pragma unroll
    for (int j = 0; j < 96; j++) whh2[j] = pk[base + j * 512];
    #pragma unroll
    for (int j = 0; j < 48; j++) wih2[j] = pk[base + (96 + j) * 512];
    #pragma unroll
    for (int j = 0; j < 16; j++) wselo[j] = pk[base + (144 + j) * 512];
    #pragma unroll
    for (int j = 0; j < 16; j++) wselp[j] = pk[base + (160 + j) * 512];
    #pragma unroll
    for (int j = 0; j < 16; j++) wout2[j] = pk[base + (176 + j) * 512];
    #pragma unroll
    for (int j = 0; j < 96; j++) asm volatile("" : "+v"(whh2[j]));
    #pragma unroll
    for (int j = 0; j < 48; j++) asm volatile("" : "+v"(wih2[j]));
    #pragma unroll
    for (int j = 0; j < 16; j++) asm volatile("" : "+v"(wselo[j]));
    #pragma unroll
    for (int j = 0; j < 16; j++) asm volatile("" : "+v"(wselp[j]));
    #pragma unroll
    for (int j = 0; j < 16; j++) asm volatile("" : "+v"(wout2[j]));

    // ---- biases ----
    float bias_r = 0.f, bias_z = 0.f, bias_in = 0.f, bias_hn = 0.f, bsel_d = 0.f, bout_o = 0.f;
    if (tid < 128) {
        int gr = role * 128 + d;
        bias_r  = bih[gr]       + bhh[gr];
        bias_z  = bih[256 + gr] + bhh[256 + gr];
        bias_in = bih[512 + gr];
        bias_hn = bhh[512 + gr];
        bsel_d  = bsel[d];
    }
    if (tid < 64) bout_o = bout[role * 64 + tid];

    // ---- init: h=0, wx=x[:,0,:], selw[0]=1 ----
    if (tid < 128) {
        h2u[tid] = 0u;
        float x0 = x[(size_t)row * Tt * Ff + tid];
        float xp = __shfl_xor(x0, 1, 64);
        if (!(tid & 1)) {
            U32H2 v; v.h = (half2_t){ (_Float16)x0, (_Float16)xp };
            wxu[tid >> 1] = v.u;
        }
        if (role == 0) selw[(size_t)row * Ff + tid] = 1.0f;
    }
    __syncthreads();

    unsigned* flags = wsu + P_FLAG;
    unsigned* hx    = wsu + P_HX;
    unsigned* pflag = &flags[row * 2 + (role ^ 1)];

    float h_old = 0.f, ssum = 0.f;
    size_t xbase  = ((size_t)row * Tt + 1) * Ff + d;
    size_t nzbase = (size_t)row * Ff + d;
    size_t swbase = ((size_t)Bb + row) * Ff + d;
    size_t obase  = (size_t)row * Oo + role * 64 + orow;   // tid<64

    const uint4* h4 = (const uint4*)h2u;
    const uint4* w4 = (const uint4*)wxu;

    for (int t = 0; t < Tt; ++t) {
        const unsigned mbMy = ((unsigned)(t & 1) * 256u + (unsigned)(row * 2 + role)) * HXS;
        const unsigned mbP  = ((unsigned)(t & 1) * 256u + (unsigned)(row * 2 + (role ^ 1))) * HXS;

        // prefetch inputs (consumed in PH6; ack waits deferred to next B2)
        float xv = 0.f, nzv = 0.f;
        if (tid < 128 && t < Tt - 1) { xv = x[xbase]; nzv = noise[nzbase]; }

        // ---- PH1: gate partials over full h(t-1) + gi over wx(t) ----
        float a_r = 0.f, a_z = 0.f, a_in = 0.f, a_hn = 0.f;
        #pragma unroll
        for (int pp = 0; pp < 8; ++pp) {
            uint4 hv = h4[8 * q + pp];
            unsigned hh[4] = { hv.x, hv.y, hv.z, hv.w };
            #pragma unroll
            for (int i = 0; i < 4; i++) {
                a_r  = dot2f(whh2[pp * 4 + i],      hh[i], a_r);
                a_z  = dot2f(whh2[32 + pp * 4 + i], hh[i], a_z);
                a_hn = dot2f(whh2[64 + pp * 4 + i], hh[i], a_hn);
            }
        }
        #pragma unroll
        for (int pp = 0; pp < 4; ++pp) {
            uint4 wv = w4[4 * q + pp];
            unsigned ww[4] = { wv.x, wv.y, wv.z, wv.w };
            #pragma unroll
            for (int i = 0; i < 4; i++) {
                a_r  = dot2f(wih2[pp * 4 + i],      ww[i], a_r);
                a_z  = dot2f(wih2[16 + pp * 4 + i], ww[i], a_z);
                a_in = dot2f(wih2[32 + pp * 4 + i], ww[i], a_in);
            }
        }
        red[tid * 5 + 0] = a_r; red[tid * 5 + 1] = a_z;
        red[tid * 5 + 2] = a_in; red[tid * 5 + 3] = a_hn;
        BAR_LGKM();                                    // B1 (LDS only)

        // ---- PH2: finalize own h-half; LDS + mailbox ----
        if (tid < 128) {
            float rr = bias_r, zz = bias_z, ii = bias_in, hh = bias_hn;
            #pragma unroll
            for (int qq = 0; qq < 4; qq++) {
                int b0 = (qq * 128 + d) * 5;
                rr += red[b0]; zz += red[b0 + 1]; ii += red[b0 + 2]; hh += red[b0 + 3];
            }
            float r = 1.f / (1.f + expf(-rr));
            float z = 1.f / (1.f + expf(-zz));
            float n = tanhf(ii + r * hh);
            float hn2 = (1.f - z) * n + z * h_old;
            h_old = hn2;
            float hp = __shfl_xor(hn2, 1, 64);
            if (!(d & 1)) {
                U32H2 v; v.h = (half2_t){ (_Float16)hn2, (_Float16)hp };
                h2u[role * 64 + (d >> 1)] = v.u;
                __hip_atomic_store(&hx[mbMy + (d >> 1)], v.u,
                                   __ATOMIC_RELAXED, __HIP_MEMORY_SCOPE_AGENT);
            }
        }
        // B2: waves 0-1 drain their mailbox stores (flag ordering); others LDS-only
        if (tid < 128) asm volatile("s_waitcnt vmcnt(0) lgkmcnt(0)" ::: "memory");
        else           asm volatile("s_waitcnt lgkmcnt(0)" ::: "memory");
        __builtin_amdgcn_s_barrier();
        asm volatile("" ::: "memory");

        // flag after B2 -> ordered after mailbox data is globally visible
        if (tid == 0)
            __hip_atomic_store(&flags[row * 2 + role], (unsigned)(t + 1),
                               __ATOMIC_RELAXED, __HIP_MEMORY_SCOPE_AGENT);

        // ---- PH3: sel/out partials over OWN half (message in flight) ----
        float p_sel = 0.f, p_out = 0.f;
        #pragma unroll
        for (int mm = 0; mm < 4; ++mm) {
            uint4 hv = h4[role * 16 + q * 4 + mm];
            unsigned hh2[4] = { hv.x, hv.y, hv.z, hv.w };
            #pragma unroll
            for (int i = 0; i < 4; i++) p_sel = dot2f(wselo[mm * 4 + i], hh2[i], p_sel);
        }
        if ((oct >> 2) == role) {
            #pragma unroll
            for (int mm = 0; mm < 4; ++mm) {
                uint4 hv = h4[oct * 4 + mm];
                unsigned hh2[4] = { hv.x, hv.y, hv.z, hv.w };
                #pragma unroll
                for (int i = 0; i < 4; i++) p_out = dot2f(wout2[mm * 4 + i], hh2[i], p_out);
            }
        }

        // ---- PH4: poll partner; fence; then load its h-half ----
        if (tid < 64) {
            while (__hip_atomic_load(pflag, __ATOMIC_RELAXED, __HIP_MEMORY_SCOPE_AGENT)
                   < (unsigned)(t + 1))
                __builtin_amdgcn_s_sleep(1);
            asm volatile("" ::: "memory");   // forbid hoisting the data load above the spin
            unsigned pv = __hip_atomic_load(&hx[mbP + tid],
                                            __ATOMIC_RELAXED, __HIP_MEMORY_SCOPE_AGENT);
            h2u[(role ^ 1) * 64 + tid] = pv;
        }
        BAR_LGKM();                                    // B3

        // ---- PH5: partner-half partials ----
        #pragma unroll
        for (int mm = 0; mm < 4; ++mm) {
            uint4 hv = h4[(role ^ 1) * 16 + q * 4 + mm];
            unsigned hh2[4] = { hv.x, hv.y, hv.z, hv.w };
            #pragma unroll
            for (int i = 0; i < 4; i++) p_sel = dot2f(wselp[mm * 4 + i], hh2[i], p_sel);
        }
        if ((oct >> 2) != role) {
            #pragma unroll
            for (int mm = 0; mm < 4; ++mm) {
                uint4 hv = h4[oct * 4 + mm];
                unsigned hh2[4] = { hv.x, hv.y, hv.z, hv.w };
                #pragma unroll
                for (int i = 0; i < 4; i++) p_out = dot2f(wout2[mm * 4 + i], hh2[i], p_out);
            }
        }
        red[tid * 5 + 0] = p_sel; red[tid * 5 + 1] = p_out;
        BAR_LGKM();                                    // B4

        // ---- PH6: outputs, w, wx (global store acks NOT drained here) ----
        if (tid < 64) {
            float acc = bout_o;
            #pragma unroll
            for (int j = 0; j < 8; j++) acc += red[(j * 64 + tid) * 5 + 1];
            outputs[obase] = acc;
        }
        if (tid < 128 && t < Tt - 1) {
            float lg = bsel_d;
            #pragma unroll
            for (int qq = 0; qq < 4; qq++) lg += red[(qq * 128 + d) * 5 + 0];
            float arg = (lg + logf(nzv + 1e-20f) - logf(1.f - nzv + 1e-20f)) * 20.0f;
            float w = 1.f / (1.f + expf(-arg));
            if (role == 0) { selw[swbase] = w; ssum += w; }
            float wxv = w * xv;
            float wp = __shfl_xor(wxv, 1, 64);
            if (!(d & 1)) {
                U32H2 v; v.h = (half2_t){ (_Float16)wxv, (_Float16)wp };
                wxu[d >> 1] = v.u;
            }
        }
        BAR_LGKM();                                    // B5 (wxu visible for next PH1)

        obase += (size_t)Bb * Oo; nzbase += (size_t)Bb * Ff;
        swbase += (size_t)Bb * Ff; xbase += Ff;
    }

    // ---- per-row selection-sum partial (role 0 only) ----
    if (role == 0) {
        red[tid] = (tid < 128) ? ssum : 0.f;
        __syncthreads();
        for (int s = 256; s > 0; s >>= 1) {
            if (tid < s) red[tid] += red[tid + s];
            __syncthreads();
        }
        if (tid == 0) partials[row] = red[0];
    }
}

__global__ void finalize_kernel(const float* __restrict__ partials, float* __restrict__ out_scalar) {
    __shared__ float red[128];
    int t = threadIdx.x;
    red[t] = partials[t];
    __syncthreads();
    for (int s = 64; s > 0; s >>= 1) {
        if (t < s) red[t] += red[t + s];
        __syncthreads();
    }
    if (t == 0) out_scalar[0] = red[0];
}

extern "C" void kernel_launch(void* const* d_in, const int* in_sizes, int n_in,
                              void* d_out, int out_size, void* d_ws, size_t ws_size,
                              hipStream_t stream) {
    const float* x     = (const float*)d_in[0];
    const float* noise = (const float*)d_in[1];
    const float* w_ih  = (const float*)d_in[2];
    const float* w_hh  = (const float*)d_in[3];
    const float* b_ih  = (const float*)d_in[4];
    const float* b_hh  = (const float*)d_in[5];
    const float* W_out = (const float*)d_in[6];
    const float* b_out = (const float*)d_in[7];
    const float* W_sel = (const float*)d_in[8];
    const float* b_sel = (const float*)d_in[9];

    unsigned* wsu = (unsigned*)d_ws;
    float* out = (float*)d_out;
    float* outputs = out;                               // [T,B,O]
    float* nsel    = out + (size_t)Tt * Bb * Oo;        // scalar
    float* selw    = nsel + 1;                          // [T,B,F]
    float* partials = (float*)(wsu + P_PART);

    pack_kernel<<<(2 * NW * 512 + 255) / 256, 256, 0, stream>>>(w_ih, w_hh, W_sel, W_out, wsu);
    zero_flags<<<1, 256, 0, stream>>>(wsu + P_FLAG);
    gru_kernel<<<256, 512, 0, stream>>>(x, noise, b_ih, b_hh, b_out, b_sel,
                                        wsu, outputs, selw, partials);
    finalize_kernel<<<1, 128, 0, stream>>>(partials, nsel);
}

// Round 12
// 3744.596 us; speedup vs baseline: 3.2619x; 1.2341x over previous
//
#include <hip/hip_runtime.h>
#include <math.h>

#define Bb 128
#define Tt 1024
#define Ff 128
#define Hh 256
#define Oo 128

#define NW 192u  // resident weight u32s per thread

// d_ws layout (u32 words)
#define P_PACK 0u
#define PACK_SZ  (2u * NW * 512u)          // 196608
#define P_HX   (P_PACK + PACK_SZ)          // [parity2][256 blk][64] u64 tagged entries
#define HX_U32 (2u * 256u * 64u * 2u)      // 65536 u32
#define P_PART (P_HX + HX_U32)

typedef _Float16 half2_t __attribute__((ext_vector_type(2)));
union U32H2 { unsigned u; half2_t h; };

__device__ __forceinline__ float dot2f(unsigned wu, unsigned hu, float acc) {
    U32H2 a, b; a.u = wu; b.u = hu;
#if __has_builtin(__builtin_amdgcn_fdot2)
    return __builtin_amdgcn_fdot2(a.h, b.h, acc, false);
#else
    return acc + (float)a.h.x * (float)b.h.x + (float)a.h.y * (float)b.h.y;
#endif
}

// LDS-only barrier: global store acks / prefetch loads stay in flight.
#define BAR_LGKM() do {                                              \
    asm volatile("s_waitcnt lgkmcnt(0)" ::: "memory");               \
    __builtin_amdgcn_s_barrier();                                    \
    asm volatile("" ::: "memory");                                   \
} while (0)

// Pack: dst[(role*NW + j)*512 + tid]; keys d=tid&127, q=tid>>7, orow=tid&63, oct=tid>>6
// j [0,48)   : whh OWN-half  g=j>>4, m=j&15 -> row g*256+role*128+d, k-u32 role*64+q*16+m
// j [48,96)  : whh PART-half g,m of j-48    -> k-u32 (1-role)*64+q*16+m
// j [96,144) : wih g=(j-96)>>4, m&15        -> row g*256+role*128+d, k-u32 16q+m
// j [144,160): wsel OWN-half  row d, k-u32 role*64+q*16+(j-144)
// j [160,176): wsel PART-half row d, k-u32 (1-role)*64+q*16+(j-160)
// j [176,192): wout row role*64+orow, k-u32 oct*16+(j-176)
__global__ void pack_kernel(const float* __restrict__ wih, const float* __restrict__ whh,
                            const float* __restrict__ wsel, const float* __restrict__ wout,
                            unsigned* __restrict__ dst) {
    unsigned pid = blockIdx.x * 256 + threadIdx.x;
    if (pid >= 2u * NW * 512u) return;
    int tid = pid & 511;
    int j = (pid >> 9) % NW;
    int role = pid / (NW * 512u);
    int d = tid & 127, q = tid >> 7;
    int orow = tid & 63, oct = tid >> 6;
    const float* src; int idx0;
    if (j < 48) {
        int g = j >> 4, m = j & 15;
        int R = g * 256 + role * 128 + d;
        src = whh; idx0 = R * 256 + 2 * (role * 64 + q * 16 + m);
    } else if (j < 96) {
        int jj = j - 48, g = jj >> 4, m = jj & 15;
        int R = g * 256 + role * 128 + d;
        src = whh; idx0 = R * 256 + 2 * ((1 - role) * 64 + q * 16 + m);
    } else if (j < 144) {
        int jj = j - 96, g = jj >> 4, m = jj & 15;
        int R = g * 256 + role * 128 + d;
        src = wih; idx0 = R * 128 + 2 * (16 * q + m);
    } else if (j < 160) {
        int jj = j - 144;
        src = wsel; idx0 = d * 256 + 2 * (role * 64 + q * 16 + jj);
    } else if (j < 176) {
        int jj = j - 160;
        src = wsel; idx0 = d * 256 + 2 * ((1 - role) * 64 + q * 16 + jj);
    } else {
        int jj = j - 176;
        int R = role * 64 + orow;
        src = wout; idx0 = R * 256 + 2 * (oct * 16 + jj);
    }
    U32H2 v; v.h = (half2_t){ (_Float16)src[idx0], (_Float16)src[idx0 + 1] };
    dst[pid] = v.u;
}

// Zero the tagged-mailbox region (stale tags from a previous replay would
// satisfy the poll). 65536 u32.
__global__ void zero_hx(unsigned* __restrict__ hx) {
    hx[blockIdx.x * 256 + threadIdx.x] = 0u;
}

__global__ __launch_bounds__(512)
void gru_kernel(const float* __restrict__ x, const float* __restrict__ noise,
                const float* __restrict__ bih, const float* __restrict__ bhh,
                const float* __restrict__ bout, const float* __restrict__ bsel,
                unsigned* __restrict__ wsu,
                float* __restrict__ outputs, float* __restrict__ selw,
                float* __restrict__ partials) {
    const int bid = blockIdx.x;
    const int row = bid & 127;
    const int role = bid >> 7;            // pair (row, row+128)
    const int tid = threadIdx.x;
    const int d = tid & 127, q = tid >> 7;
    const int orow = tid & 63, oct = tid >> 6;

    __shared__ unsigned h2u[128];         // full h as fp16 pairs
    __shared__ unsigned wxu[64];          // gated input as fp16 pairs
    __shared__ float red[512 * 5];        // stride-5 padded partials

    // ---- resident weights ----
    unsigned whho[48], whhp[48], wih2[48], wselo[16], wselp[16], wout2[16];
    const unsigned base = (unsigned)(role * NW) * 512u + (unsigned)tid;
    const unsigned* __restrict__ pk = wsu + P_PACK;
    #pragma unroll
    for (int j = 0; j < 48; j++) whho[j] = pk[base + j * 512];
    #pragma unroll
    for (int j = 0; j < 48; j++) whhp[j] = pk[base + (48 + j) * 512];
    #pragma unroll
    for (int j = 0; j < 48; j++) wih2[j] = pk[base + (96 + j) * 512];
    #pragma unroll
    for (int j = 0; j < 16; j++) wselo[j] = pk[base + (144 + j) * 512];
    #pragma unroll
    for (int j = 0; j < 16; j++) wselp[j] = pk[base + (160 + j) * 512];
    #pragma unroll
    for (int j = 0; j < 16; j++) wout2[j] = pk[base + (176 + j) * 512];
    #pragma unroll
    for (int j = 0; j < 48; j++) asm volatile("" : "+v"(whho[j]));
    #pragma unroll
    for (int j = 0; j < 48; j++) asm volatile("" : "+v"(whhp[j]));
    #pragma unroll
    for (int j = 0; j < 48; j++) asm volatile("" : "+v"(wih2[j]));
    #pragma unroll
    for (int j = 0; j < 16; j++) asm volatile("" : "+v"(wselo[j]));
    #pragma unroll
    for (int j = 0; j < 16; j++) asm volatile("" : "+v"(wselp[j]));
    #pragma unroll
    for (int j = 0; j < 16; j++) asm volatile("" : "+v"(wout2[j]));

    // ---- biases ----
    float bias_r = 0.f, bias_z = 0.f, bias_in = 0.f, bias_hn = 0.f, bsel_d = 0.f, bout_o = 0.f;
    if (tid < 128) {
        int gr = role * 128 + d;
        bias_r  = bih[gr]       + bhh[gr];
        bias_z  = bih[256 + gr] + bhh[256 + gr];
        bias_in = bih[512 + gr];
        bias_hn = bhh[512 + gr];
        bsel_d  = bsel[d];
    }
    if (tid < 64) bout_o = bout[role * 64 + tid];

    // ---- init: h=0, wx=x[:,0,:], selw[0]=1, a_own=0 ----
    if (tid < 128) {
        h2u[tid] = 0u;
        float x0 = x[(size_t)row * Tt * Ff + tid];
        float xp = __shfl_xor(x0, 1, 64);
        if (!(tid & 1)) {
            U32H2 v; v.h = (half2_t){ (_Float16)x0, (_Float16)xp };
            wxu[tid >> 1] = v.u;
        }
        if (role == 0) selw[(size_t)row * Ff + tid] = 1.0f;
    }
    __syncthreads();

    unsigned long long* hxq = (unsigned long long*)(wsu + P_HX);

    float h_old = 0.f, ssum = 0.f;
    float aor = 0.f, aoz = 0.f, aohn = 0.f;   // gh own-half partials for step t (pipelined)
    size_t xbase  = ((size_t)row * Tt + 1) * Ff + d;
    size_t nzbase = (size_t)row * Ff + d;
    size_t swbase = ((size_t)Bb + row) * Ff + d;
    size_t obase  = (size_t)row * Oo + role * 64 + orow;   // tid<64

    const uint4* h4 = (const uint4*)h2u;
    const uint4* w4 = (const uint4*)wxu;

    for (int t = 0; t < Tt; ++t) {
        const unsigned mbMy = ((unsigned)(t & 1) * 256u + (unsigned)(row * 2 + role)) * 64u;
        const unsigned mbP  = ((unsigned)(t & 1) * 256u + (unsigned)(row * 2 + (role ^ 1))) * 64u;

        // ---- PH1: gates(t) = a_own (pipelined) + gh_partner + gi ----
        float a_r = aor, a_z = aoz, a_in = 0.f, a_hn = aohn;
        #pragma unroll
        for (int mm = 0; mm < 4; ++mm) {
            uint4 hv = h4[(role ^ 1) * 16 + q * 4 + mm];
            unsigned hh[4] = { hv.x, hv.y, hv.z, hv.w };
            #pragma unroll
            for (int i = 0; i < 4; i++) {
                a_r  = dot2f(whhp[mm * 4 + i],      hh[i], a_r);
                a_z  = dot2f(whhp[16 + mm * 4 + i], hh[i], a_z);
                a_hn = dot2f(whhp[32 + mm * 4 + i], hh[i], a_hn);
            }
        }
        #pragma unroll
        for (int pp = 0; pp < 4; ++pp) {
            uint4 wv = w4[4 * q + pp];
            unsigned ww[4] = { wv.x, wv.y, wv.z, wv.w };
            #pragma unroll
            for (int i = 0; i < 4; i++) {
                a_r  = dot2f(wih2[pp * 4 + i],      ww[i], a_r);
                a_z  = dot2f(wih2[16 + pp * 4 + i], ww[i], a_z);
                a_in = dot2f(wih2[32 + pp * 4 + i], ww[i], a_in);
            }
        }
        red[tid * 5 + 0] = a_r; red[tid * 5 + 1] = a_z;
        red[tid * 5 + 2] = a_in; red[tid * 5 + 3] = a_hn;
        BAR_LGKM();                                    // B1

        // ---- PH2: finalize h_own(t); LDS + tagged publish (no drain, no flag) ----
        if (tid < 128) {
            float rr = bias_r, zz = bias_z, ii = bias_in, hh = bias_hn;
            #pragma unroll
            for (int qq = 0; qq < 4; qq++) {
                int b0 = (qq * 128 + d) * 5;
                rr += red[b0]; zz += red[b0 + 1]; ii += red[b0 + 2]; hh += red[b0 + 3];
            }
            float r = 1.f / (1.f + expf(-rr));
            float z = 1.f / (1.f + expf(-zz));
            float n = tanhf(ii + r * hh);
            float hn2 = (1.f - z) * n + z * h_old;
            h_old = hn2;
            float hp = __shfl_xor(hn2, 1, 64);
            if (!(d & 1)) {
                U32H2 v; v.h = (half2_t){ (_Float16)hn2, (_Float16)hp };
                h2u[role * 64 + (d >> 1)] = v.u;
                unsigned long long msg = ((unsigned long long)(unsigned)(t + 1) << 32) | v.u;
                __hip_atomic_store(&hxq[mbMy + (unsigned)(d >> 1)], msg,
                                   __ATOMIC_RELAXED, __HIP_MEMORY_SCOPE_AGENT);
            }
        }
        BAR_LGKM();                                    // B2 (h_own visible in LDS)

        // ---- PH3 (flight window): prefetch inputs; gh_own(t+1); sel/out own ----
        float xv = 0.f, nzv = 0.f;
        if (tid < 128 && t < Tt - 1) { xv = x[xbase]; nzv = noise[nzbase]; }

        aor = 0.f; aoz = 0.f; aohn = 0.f;
        float p_sel = 0.f, p_out = 0.f;
        #pragma unroll
        for (int mm = 0; mm < 4; ++mm) {
            uint4 hv = h4[role * 16 + q * 4 + mm];
            unsigned hh[4] = { hv.x, hv.y, hv.z, hv.w };
            #pragma unroll
            for (int i = 0; i < 4; i++) {
                aor  = dot2f(whho[mm * 4 + i],      hh[i], aor);
                aoz  = dot2f(whho[16 + mm * 4 + i], hh[i], aoz);
                aohn = dot2f(whho[32 + mm * 4 + i], hh[i], aohn);
                p_sel = dot2f(wselo[mm * 4 + i], hh[i], p_sel);
            }
        }
        if ((oct >> 2) == role) {
            #pragma unroll
            for (int mm = 0; mm < 4; ++mm) {
                uint4 hv = h4[oct * 4 + mm];
                unsigned hh[4] = { hv.x, hv.y, hv.z, hv.w };
                #pragma unroll
                for (int i = 0; i < 4; i++) p_out = dot2f(wout2[mm * 4 + i], hh[i], p_out);
            }
        }

        // ---- PH4: poll tagged partner entries (single visibility hop) ----
        if (tid < 64) {
            unsigned long long msg;
            do {
                msg = __hip_atomic_load(&hxq[mbP + (unsigned)tid],
                                        __ATOMIC_RELAXED, __HIP_MEMORY_SCOPE_AGENT);
                if ((unsigned)(msg >> 32) >= (unsigned)(t + 1)) break;
                __builtin_amdgcn_s_sleep(1);
            } while (1);
            h2u[(role ^ 1) * 64 + tid] = (unsigned)msg;
        }
        BAR_LGKM();                                    // B3

        // ---- PH5: partner-half sel/out partials ----
        #pragma unroll
        for (int mm = 0; mm < 4; ++mm) {
            uint4 hv = h4[(role ^ 1) * 16 + q * 4 + mm];
            unsigned hh[4] = { hv.x, hv.y, hv.z, hv.w };
            #pragma unroll
            for (int i = 0; i < 4; i++) p_sel = dot2f(wselp[mm * 4 + i], hh[i], p_sel);
        }
        if ((oct >> 2) != role) {
            #pragma unroll
            for (int mm = 0; mm < 4; ++mm) {
                uint4 hv = h4[oct * 4 + mm];
                unsigned hh[4] = { hv.x, hv.y, hv.z, hv.w };
                #pragma unroll
                for (int i = 0; i < 4; i++) p_out = dot2f(wout2[mm * 4 + i], hh[i], p_out);
            }
        }
        red[tid * 5 + 0] = p_sel; red[tid * 5 + 1] = p_out;
        BAR_LGKM();                                    // B4

        // ---- PH6: outputs(t) [off critical path], w(t+1), wx(t+1) ----
        if (tid < 64) {
            float acc = bout_o;
            #pragma unroll
            for (int j = 0; j < 8; j++) acc += red[(j * 64 + tid) * 5 + 1];
            outputs[obase] = acc;
        }
        if (tid < 128 && t < Tt - 1) {
            float lg = bsel_d;
            #pragma unroll
            for (int qq = 0; qq < 4; qq++) lg += red[(qq * 128 + d) * 5 + 0];
            float arg = (lg + logf(nzv + 1e-20f) - logf(1.f - nzv + 1e-20f)) * 20.0f;
            float w = 1.f / (1.f + expf(-arg));
            if (role == 0) { selw[swbase] = w; ssum += w; }
            float wxv = w * xv;
            float wp = __shfl_xor(wxv, 1, 64);
            if (!(d & 1)) {
                U32H2 v; v.h = (half2_t){ (_Float16)wxv, (_Float16)wp };
                wxu[d >> 1] = v.u;
            }
        }
        BAR_LGKM();                                    // B5 (wxu ready for next PH1)

        obase += (size_t)Bb * Oo; nzbase += (size_t)Bb * Ff;
        swbase += (size_t)Bb * Ff; xbase += Ff;
    }

    // ---- per-row selection-sum partial (role 0 only) ----
    if (role == 0) {
        red[tid] = (tid < 128) ? ssum : 0.f;
        __syncthreads();
        for (int s = 256; s > 0; s >>= 1) {
            if (tid < s) red[tid] += red[tid + s];
            __syncthreads();
        }
        if (tid == 0) partials[row] = red[0];
    }
}

__global__ void finalize_kernel(const float* __restrict__ partials, float* __restrict__ out_scalar) {
    __shared__ float red[128];
    int t = threadIdx.x;
    red[t] = partials[t];
    __syncthreads();
    for (int s = 64; s > 0; s >>= 1) {
        if (t < s) red[t] += red[t + s];
        __syncthreads();
    }
    if (t == 0) out_scalar[0] = red[0];
}

extern "C" void kernel_launch(void* const* d_in, const int* in_sizes, int n_in,
                              void* d_out, int out_size, void* d_ws, size_t ws_size,
                              hipStream_t stream) {
    const float* x     = (const float*)d_in[0];
    const float* noise = (const float*)d_in[1];
    const float* w_ih  = (const float*)d_in[2];
    const float* w_hh  = (const float*)d_in[3];
    const float* b_ih  = (const float*)d_in[4];
    const float* b_hh  = (const float*)d_in[5];
    const float* W_out = (const float*)d_in[6];
    const float* b_out = (const float*)d_in[7];
    const float* W_sel = (const float*)d_in[8];
    const float* b_sel = (const float*)d_in[9];

    unsigned* wsu = (unsigned*)d_ws;
    float* out = (float*)d_out;
    float* outputs = out;                               // [T,B,O]
    float* nsel    = out + (size_t)Tt * Bb * Oo;        // scalar
    float* selw    = nsel + 1;                          // [T,B,F]
    float* partials = (float*)(wsu + P_PART);

    pack_kernel<<<(2 * NW * 512 + 255) / 256, 256, 0, stream>>>(w_ih, w_hh, W_sel, W_out, wsu);
    zero_hx<<<HX_U32 / 256, 256, 0, stream>>>(wsu + P_HX);
    gru_kernel<<<256, 512, 0, stream>>>(x, noise, b_ih, b_hh, b_out, b_sel,
                                        wsu, outputs, selw, partials);
    finalize_kernel<<<1, 128, 0, stream>>>(partials, nsel);
}